// Round 1
// baseline (421.981 us; speedup 1.0000x reference)
//
#include <hip/hip_runtime.h>

typedef __bf16 bf16x8 __attribute__((ext_vector_type(8)));
typedef __bf16 bf16x2 __attribute__((ext_vector_type(2)));
typedef float  f32x4  __attribute__((ext_vector_type(4)));

// sizes: E=4 B=32 CI=64 H=W=64 CO=128 OH=OW=62
// ws layout: [0, 64MiB) features bf16 NHWC [eb][y][x][i]
//            [64MiB, +576KiB) weights bf16 [e][tap][j][i]
#define FT_BYTES 67108864ull

__device__ __forceinline__ void gl2lds16(const void* g, void* l) {
    __builtin_amdgcn_global_load_lds(
        (const __attribute__((address_space(1))) void*)g,
        (__attribute__((address_space(3))) void*)l, 16, 0, 0);
}

// prepass 1: weight fp32 [e][i][j][tap] -> bf16 [e][tap][j][i]
__global__ void wt_prep(const float* __restrict__ w, __bf16* __restrict__ wt) {
    int o = blockIdx.x * 256 + threadIdx.x;           // 294912 total
    int i = o & 63, j = (o >> 6) & 127, et = o >> 13; // et 0..35
    int tap = et % 9, e = et / 9;
    wt[o] = (__bf16)w[((e * 64 + i) * 128 + j) * 9 + tap];
}

// prepass 2: features fp32 NCHW -> bf16 NHWC, one block per (e,b,y)
__global__ void ft_prep(const float* __restrict__ f, __bf16* __restrict__ ft) {
    __shared__ float s[64 * 65];                      // [i][x], +1 pad
    int eb = blockIdx.z * 32 + blockIdx.y, y = blockIdx.x;
    const float* src = f + (size_t)eb * 262144 + y * 64;
    int t = threadIdx.x;
    for (int r = 0; r < 4; ++r) {
        int f4 = r * 256 + t;                         // 1024 float4
        int i = f4 >> 4, x4 = (f4 & 15) * 4;
        float4 v = *(const float4*)(src + i * 4096 + x4);
        s[i * 65 + x4 + 0] = v.x; s[i * 65 + x4 + 1] = v.y;
        s[i * 65 + x4 + 2] = v.z; s[i * 65 + x4 + 3] = v.w;
    }
    __syncthreads();
    bf16x2* dst = (bf16x2*)(ft + (size_t)(eb * 64 + y) * 4096);
    for (int r = 0; r < 8; ++r) {
        int q = r * 256 + t;                          // 2048 bf16x2; q = x*32+ih
        int x = q >> 5, ih = q & 31;
        bf16x2 pv;
        pv.x = (__bf16)s[(2 * ih + 0) * 65 + x];
        pv.y = (__bf16)s[(2 * ih + 1) * 65 + x];
        dst[q] = pv;
    }
}

// main: per block (e,b,2-row group): out tile 128(j) x 128(p=2y*64x)
// K-loop: 9 taps, BK=64 (=C_in), 2 mfma k-steps per tap.
// LDS tiles [row][64] bf16; 16B chunk g stored at slot g^(row&7) (bank swizzle).
__global__ __launch_bounds__(256, 2)
void conv_main(const __bf16* __restrict__ ft, const __bf16* __restrict__ wt,
               const float* __restrict__ bias, float* __restrict__ out) {
    __shared__ __align__(16) __bf16 sA[128 * 64];     // [j][i] 16KB
    __shared__ __align__(16) __bf16 sB[128 * 64];     // [p][i] 16KB
    const int e = blockIdx.z, b = blockIdx.y, y0 = blockIdx.x * 2;
    const int eb = e * 32 + b;
    const int t = threadIdx.x, lane = t & 63, w = t >> 6;
    const int wm = w >> 1, wn = w & 1;                // 2x2 waves over (M,N)
    const int q = lane >> 4, rm = lane & 15;

    f32x4 acc[4][4] = {};
    const __bf16* ftb = ft + (size_t)eb * 262144;

    for (int tap = 0; tap < 9; ++tap) {
        const int A = tap / 3, Bt = tap - A * 3;
        __syncthreads();                              // prev compute done before restage
        // stage A: weights for this tap, 16 chunks of 1KB, 4 per wave
        const __bf16* wtap = wt + ((size_t)(e * 9 + tap) << 13);
        for (int cc = 0; cc < 4; ++cc) {
            int c = w * 4 + cc;
            int r = c * 8 + (lane >> 3);
            int g = (lane & 7) ^ (r & 7);
            gl2lds16(wtap + r * 64 + g * 8, sA + c * 512);
        }
        // stage B: feature rows p=(py,px), x' = px+Bt clamped (dead cols only)
        const int yA = y0 + A;
        for (int cc = 0; cc < 4; ++cc) {
            int c = w * 4 + cc;
            int p = c * 8 + (lane >> 3);
            int py = p >> 6, px = p & 63;
            int xx = px + Bt; if (xx > 63) xx = 63;
            int g = (lane & 7) ^ (p & 7);
            gl2lds16(ftb + (((yA + py) * 64 + xx) << 6) + g * 8, sB + c * 512);
        }
        __syncthreads();                              // drains vmcnt(0): DMA complete
        // compute: 2 k-steps x 16 mfma
        for (int kk = 0; kk < 64; kk += 32) {
            const int kg = kk >> 3;                   // base 16B-chunk: 0 or 4
            bf16x8 af[4], bq[4];
            for (int mi = 0; mi < 4; ++mi) {
                int r = wm * 64 + mi * 16 + rm;
                int ch = (kg + q) ^ (r & 7);
                af[mi] = *(const bf16x8*)(sA + r * 64 + ch * 8);
            }
            for (int ni = 0; ni < 4; ++ni) {
                int r = wn * 64 + ni * 16 + rm;
                int ch = (kg + q) ^ (r & 7);
                bq[ni] = *(const bf16x8*)(sB + r * 64 + ch * 8);
            }
            for (int mi = 0; mi < 4; ++mi)
                for (int ni = 0; ni < 4; ++ni)
                    acc[mi][ni] = __builtin_amdgcn_mfma_f32_16x16x32_bf16(
                        af[mi], bq[ni], acc[mi][ni], 0, 0, 0);
        }
    }

    // epilogue: D layout col(n=p)=lane&15, row(m=j)=(lane>>4)*4+reg
    for (int mi = 0; mi < 4; ++mi) {
        for (int ni = 0; ni < 4; ++ni) {
            int p = wn * 64 + ni * 16 + rm;
            int py = p >> 6, px = p & 63;
            if (px >= 62) continue;                   // dead padding columns
            for (int vv = 0; vv < 4; ++vv) {
                int j = wm * 64 + mi * 16 + q * 4 + vv;
                float v = acc[mi][ni][vv] + bias[e * 128 + j];
                out[(((size_t)eb * 128 + j) * 62 + (y0 + py)) * 62 + px] = v;
            }
        }
    }
}

extern "C" void kernel_launch(void* const* d_in, const int* in_sizes, int n_in,
                              void* d_out, int out_size, void* d_ws, size_t ws_size,
                              hipStream_t stream) {
    const float* f    = (const float*)d_in[0];
    const float* wgt  = (const float*)d_in[1];
    const float* bias = (const float*)d_in[2];
    float* out = (float*)d_out;
    __bf16* ftw = (__bf16*)d_ws;
    __bf16* wtw = (__bf16*)((char*)d_ws + FT_BYTES);

    ft_prep<<<dim3(64, 32, 4), 256, 0, stream>>>(f, ftw);
    wt_prep<<<dim3(1152), 256, 0, stream>>>(wgt, wtw);
    conv_main<<<dim3(31, 32, 4), 256, 0, stream>>>(ftw, wtw, bias, out);
}